// Round 4
// baseline (157.427 us; speedup 1.0000x reference)
//
#include <hip/hip_runtime.h>
#include <math.h>

// GLIF forward scan. T=64, B=128, N=2048 (derived at runtime from in_sizes).
// All recurrence math in float64: output is 0/1 spikes with threshold 2e-2,
// one flip = fail. f64 error ~1e-16 vs closest spike margin ~1e-7 => safe.
//
// Round-4: 1 neuron/thread. Round-3's 4-neurons/thread gave only 512 waves
// (2 waves/CU, Occupancy 8.7%) -> latency-bound at 48 us. Parallelism beats
// per-lane width here: lanes are adjacent in n so coalescing is perfect at
// any width. 262144 threads = 16 waves/CU.

__device__ __forceinline__ double dsig(double x) {
    return 1.0 / (1.0 + exp(-x));
}

// Precompute kernel: one thread per (t,n) element of icoef; threads with
// i < N additionally compute the per-n constants.
// ws layout (doubles): [0,N) decay_v | [N,2N) leak_term | [2N,3N) reset_w
//                      | [3N,4N) thr | [4N,5N) ga | [5N, 5N+T*N) icoef
__global__ void glif_pre_kernel(const float* __restrict__ alpha,
                                const float* __restrict__ beta,
                                const float* __restrict__ gamma,
                                const float* __restrict__ tau,
                                const float* __restrict__ Vth,
                                const float* __restrict__ leak,
                                const float* __restrict__ reVth,
                                const float* __restrict__ conduct,
                                double* __restrict__ wsd,
                                int N, int TN) {
    int i = blockIdx.x * blockDim.x + threadIdx.x;
    if (i >= TN) return;
    int n = i % N;
    double be = dsig((double)beta[n]);
    double cs = dsig((double)conduct[i]);
    wsd[5 * N + i] = 1.0 - be * (1.0 - cs);  // icoef[t][n]
    if (i < N) {
        double al     = dsig((double)alpha[i]);
        double ga     = dsig((double)gamma[i]);
        double tau_s  = dsig((double)tau[i]);
        double vth_s  = dsig((double)Vth[i]);
        double leak_s = dsig((double)leak[i]);
        double rev_s  = dsig((double)reVth[i]);
        wsd[0 * N + i] = 1.0 - al * (1.0 - tau_s);  // decay_v
        wsd[1 * N + i] = (1.0 - al) * leak_s;       // leak_term
        wsd[2 * N + i] = (1.0 - ga) * rev_s;        // reset_w
        wsd[3 * N + i] = vth_s;                     // thr
        wsd[4 * N + i] = ga;                        // ga
    }
}

// Main scan: ONE neuron per thread (max TLP: 4096 waves = 16 waves/CU),
// sequential loop over T with 1-ahead prefetch of x and icoef.
__global__ __launch_bounds__(256) void glif_main1_kernel(
        const float* __restrict__ tx,
        const double* __restrict__ wsd,
        float* __restrict__ out,
        int T, int B, int N) {
    const int idx = blockIdx.x * blockDim.x + threadIdx.x;
    if (idx >= B * N) return;
    const int n = idx % N;  // one-time cost; N=2048 in practice

    const double dv   = wsd[0 * N + n];
    const double lt   = wsd[1 * N + n];
    const double rw   = wsd[2 * N + n];
    const double th   = wsd[3 * N + n];
    const double omga = 1.0 - wsd[4 * N + n];  // (1 - ga); exact since ga*1 == ga
    const double* icp = wsd + 5 * N + n;

    double v = 0.0;
    bool y = false;

    const float* txp = tx + idx;
    float* op = out + idx;
    const size_t stride = (size_t)B * N;

    // Prefetch t=0
    float x   = __builtin_nontemporal_load(txp);
    double ic = *icp;

#pragma unroll 4
    for (int t = 0; t < T; ++t) {
        float xn = 0.0f;
        double icn = 0.0;
        if (t + 1 < T) {  // wave-uniform; issues next loads before the chain
            xn  = __builtin_nontemporal_load(txp + stride);
            icn = icp[N];
        }

        const double I = (double)x * ic;
        const double m = y ? omga : 1.0;  // (1 - ga*y), exact for y in {0,1}
        const double r = y ? rw : 0.0;    // reset_w*y, exact
        v = dv * v * m - lt + I - r;
        y = v > th;
        __builtin_nontemporal_store(y ? 1.0f : 0.0f, op);

        x = xn; ic = icn;
        txp += stride;
        op  += stride;
        icp += N;
    }
}

// Fallback (only if ws too small): computes all sigmoids inline per thread,
// 2 neurons/thread. Same f64 expression tree.
__global__ __launch_bounds__(256) void glif_main_inline_kernel(
        const float* __restrict__ tx,
        const float* __restrict__ alpha,
        const float* __restrict__ beta,
        const float* __restrict__ gamma,
        const float* __restrict__ tau,
        const float* __restrict__ Vth,
        const float* __restrict__ leak,
        const float* __restrict__ reVth,
        const float* __restrict__ conduct,
        float* __restrict__ out,
        int T, int B, int N) {
    const int half = N >> 1;
    const int idx = blockIdx.x * blockDim.x + threadIdx.x;
    if (idx >= B * half) return;
    const int b = idx / half;
    const int n = (idx - b * half) << 1;

    const double al0 = dsig((double)alpha[n]), al1 = dsig((double)alpha[n + 1]);
    const double ga0 = dsig((double)gamma[n]), ga1 = dsig((double)gamma[n + 1]);
    const double be0 = dsig((double)beta[n]),  be1 = dsig((double)beta[n + 1]);
    const double ts0 = dsig((double)tau[n]),   ts1 = dsig((double)tau[n + 1]);
    const double th0 = dsig((double)Vth[n]),   th1 = dsig((double)Vth[n + 1]);
    const double ls0 = dsig((double)leak[n]),  ls1 = dsig((double)leak[n + 1]);
    const double rs0 = dsig((double)reVth[n]), rs1 = dsig((double)reVth[n + 1]);
    const double dv0 = 1.0 - al0 * (1.0 - ts0), dv1 = 1.0 - al1 * (1.0 - ts1);
    const double lt0 = (1.0 - al0) * ls0,       lt1 = (1.0 - al1) * ls1;
    const double rw0 = (1.0 - ga0) * rs0,       rw1 = (1.0 - ga1) * rs1;
    const double om_ga0 = 1.0 - ga0, om_ga1 = 1.0 - ga1;

    double v0 = 0.0, v1 = 0.0;
    bool y0 = false, y1 = false;

    const size_t bn = (size_t)b * N + n;
    const float* txp = tx + bn;
    float* op = out + bn;
    const float* cp = conduct + n;
    const size_t strideTx = (size_t)B * N;

    for (int t = 0; t < T; ++t) {
        const float2 x = *(const float2*)txp;
        const double ic0 = 1.0 - be0 * (1.0 - dsig((double)cp[0]));
        const double ic1 = 1.0 - be1 * (1.0 - dsig((double)cp[1]));

        const double I0 = (double)x.x * ic0;
        const double m0 = y0 ? om_ga0 : 1.0;
        const double r0 = y0 ? rw0 : 0.0;
        v0 = dv0 * v0 * m0 - lt0 + I0 - r0;
        y0 = v0 > th0;

        const double I1 = (double)x.y * ic1;
        const double m1 = y1 ? om_ga1 : 1.0;
        const double r1 = y1 ? rw1 : 0.0;
        v1 = dv1 * v1 * m1 - lt1 + I1 - r1;
        y1 = v1 > th1;

        float2 o;
        o.x = y0 ? 1.0f : 0.0f;
        o.y = y1 ? 1.0f : 0.0f;
        *(float2*)op = o;

        txp += strideTx;
        op += strideTx;
        cp += N;
    }
}

extern "C" void kernel_launch(void* const* d_in, const int* in_sizes, int n_in,
                              void* d_out, int out_size, void* d_ws, size_t ws_size,
                              hipStream_t stream) {
    const float* tx      = (const float*)d_in[0];
    const float* alpha   = (const float*)d_in[1];
    const float* beta    = (const float*)d_in[2];
    const float* gamma   = (const float*)d_in[3];
    const float* tau     = (const float*)d_in[4];
    const float* Vth     = (const float*)d_in[5];
    const float* leak    = (const float*)d_in[6];
    const float* reVth   = (const float*)d_in[7];
    const float* conduct = (const float*)d_in[8];
    float* out = (float*)d_out;

    const int N  = in_sizes[1];        // 2048
    const int TN = in_sizes[8];        // T*N = 131072
    const int T  = TN / N;             // 64
    const int B  = in_sizes[0] / TN;   // 128

    const size_t needed = (size_t)(5 * N + TN) * sizeof(double);
    if (ws_size >= needed) {
        double* wsd = (double*)d_ws;
        const int preBlocks = (TN + 255) / 256;
        glif_pre_kernel<<<preBlocks, 256, 0, stream>>>(
            alpha, beta, gamma, tau, Vth, leak, reVth, conduct, wsd, N, TN);
        const int total = B * N;
        glif_main1_kernel<<<(total + 255) / 256, 256, 0, stream>>>(
            tx, wsd, out, T, B, N);
    } else {
        const int total = B * (N >> 1);
        glif_main_inline_kernel<<<(total + 255) / 256, 256, 0, stream>>>(
            tx, alpha, beta, gamma, tau, Vth, leak, reVth, conduct,
            out, T, B, N);
    }
}

// Round 5
// 139.631 us; speedup vs baseline: 1.1274x; 1.1274x over previous
//
#include <hip/hip_runtime.h>
#include <math.h>

// GLIF forward scan. T=64, B=128, N=2048 (derived at runtime from in_sizes).
// All recurrence math in float64: output is 0/1 spikes with threshold 2e-2,
// one flip = fail. f64 error ~1e-16 vs closest spike margin ~1e-7 => safe.
//
// Round-5: deep register prefetch. r3 (4 n/thread, occ 8.7%) and r4
// (1 n/thread, occ 36%) both sat at ~50 us / 2 TB/s -> bottleneck is
// per-wave MLP, not occupancy: with 1-ahead prefetch each iteration waits
// ~1800 cyc on one x-load. Fix: double-buffered blocks of 8 time steps in
// registers; 8 x-loads + 8 ic-loads in flight while computing the previous
// 8 steps from registers (fine-grained vmcnt pattern).

__device__ __forceinline__ double dsig(double x) {
    return 1.0 / (1.0 + exp(-x));
}

// Precompute kernel: one thread per (t,n) element of icoef; threads with
// i < N additionally compute the per-n constants.
// ws layout (doubles): [0,N) decay_v | [N,2N) leak_term | [2N,3N) reset_w
//                      | [3N,4N) thr | [4N,5N) ga | [5N, 5N+T*N) icoef
__global__ void glif_pre_kernel(const float* __restrict__ alpha,
                                const float* __restrict__ beta,
                                const float* __restrict__ gamma,
                                const float* __restrict__ tau,
                                const float* __restrict__ Vth,
                                const float* __restrict__ leak,
                                const float* __restrict__ reVth,
                                const float* __restrict__ conduct,
                                double* __restrict__ wsd,
                                int N, int TN) {
    int i = blockIdx.x * blockDim.x + threadIdx.x;
    if (i >= TN) return;
    int n = i % N;
    double be = dsig((double)beta[n]);
    double cs = dsig((double)conduct[i]);
    wsd[5 * N + i] = 1.0 - be * (1.0 - cs);  // icoef[t][n]
    if (i < N) {
        double al     = dsig((double)alpha[i]);
        double ga     = dsig((double)gamma[i]);
        double tau_s  = dsig((double)tau[i]);
        double vth_s  = dsig((double)Vth[i]);
        double leak_s = dsig((double)leak[i]);
        double rev_s  = dsig((double)reVth[i]);
        wsd[0 * N + i] = 1.0 - al * (1.0 - tau_s);  // decay_v
        wsd[1 * N + i] = (1.0 - al) * leak_s;       // leak_term
        wsd[2 * N + i] = (1.0 - ga) * rev_s;        // reset_w
        wsd[3 * N + i] = vth_s;                     // thr
        wsd[4 * N + i] = ga;                        // ga
    }
}

// Main scan: one neuron/thread, T blocked by D=8 with register double-buffer.
__global__ __launch_bounds__(256) void glif_main_pf_kernel(
        const float* __restrict__ tx,
        const double* __restrict__ wsd,
        float* __restrict__ out,
        int T, int B, int N) {
    constexpr int D = 8;
    const int idx = blockIdx.x * blockDim.x + threadIdx.x;
    if (idx >= B * N) return;
    const int n = idx % N;

    const double dv   = wsd[0 * N + n];
    const double lt   = wsd[1 * N + n];
    const double rw   = wsd[2 * N + n];
    const double th   = wsd[3 * N + n];
    const double omga = 1.0 - wsd[4 * N + n];  // (1 - ga); exact since ga*1 == ga

    const size_t stride = (size_t)B * N;
    const float*  txp = tx + idx;
    const double* icp = wsd + 5 * N + n;
    float* op = out + idx;

    double v = 0.0;
    bool y = false;

    const int nblk = T / D;

    float  xa[D], xb[D];
    double ica[D], icb[D];

    // Load block 0 (8 independent loads in flight immediately).
#pragma unroll
    for (int j = 0; j < D; ++j) {
        xa[j]  = txp[(size_t)j * stride];
        ica[j] = icp[(size_t)j * N];
    }

    for (int blk = 0; blk < nblk; ++blk) {
        const float*  txn = txp + (size_t)D * stride;
        const double* icn = icp + (size_t)D * N;
        const bool more = (blk + 1 < nblk);
        if (more) {
            // Issue next block's 16 loads before touching this block's data:
            // they stay outstanding across the whole compute chain below.
#pragma unroll
            for (int j = 0; j < D; ++j) {
                xb[j]  = txn[(size_t)j * stride];
                icb[j] = icn[(size_t)j * N];
            }
        }

#pragma unroll
        for (int j = 0; j < D; ++j) {
            const double I = (double)xa[j] * ica[j];
            const double m = y ? omga : 1.0;  // (1 - ga*y), exact for y in {0,1}
            const double r = y ? rw : 0.0;    // reset_w*y, exact
            v = dv * v * m - lt + I - r;
            y = v > th;
            __builtin_nontemporal_store(y ? 1.0f : 0.0f, op + (size_t)j * stride);
        }

        if (more) {
#pragma unroll
            for (int j = 0; j < D; ++j) { xa[j] = xb[j]; ica[j] = icb[j]; }
        }
        txp = txn; icp = icn; op += (size_t)D * stride;
    }

    // Remainder if T % D != 0 (dead for T=64).
    for (int t = nblk * D; t < T; ++t) {
        const double I = (double)(*txp) * (*icp);
        const double m = y ? omga : 1.0;
        const double r = y ? rw : 0.0;
        v = dv * v * m - lt + I - r;
        y = v > th;
        __builtin_nontemporal_store(y ? 1.0f : 0.0f, op);
        txp += stride; icp += N; op += stride;
    }
}

// Fallback (only if ws too small): computes all sigmoids inline per thread,
// 2 neurons/thread. Same f64 expression tree.
__global__ __launch_bounds__(256) void glif_main_inline_kernel(
        const float* __restrict__ tx,
        const float* __restrict__ alpha,
        const float* __restrict__ beta,
        const float* __restrict__ gamma,
        const float* __restrict__ tau,
        const float* __restrict__ Vth,
        const float* __restrict__ leak,
        const float* __restrict__ reVth,
        const float* __restrict__ conduct,
        float* __restrict__ out,
        int T, int B, int N) {
    const int half = N >> 1;
    const int idx = blockIdx.x * blockDim.x + threadIdx.x;
    if (idx >= B * half) return;
    const int b = idx / half;
    const int n = (idx - b * half) << 1;

    const double al0 = dsig((double)alpha[n]), al1 = dsig((double)alpha[n + 1]);
    const double ga0 = dsig((double)gamma[n]), ga1 = dsig((double)gamma[n + 1]);
    const double be0 = dsig((double)beta[n]),  be1 = dsig((double)beta[n + 1]);
    const double ts0 = dsig((double)tau[n]),   ts1 = dsig((double)tau[n + 1]);
    const double th0 = dsig((double)Vth[n]),   th1 = dsig((double)Vth[n + 1]);
    const double ls0 = dsig((double)leak[n]),  ls1 = dsig((double)leak[n + 1]);
    const double rs0 = dsig((double)reVth[n]), rs1 = dsig((double)reVth[n + 1]);
    const double dv0 = 1.0 - al0 * (1.0 - ts0), dv1 = 1.0 - al1 * (1.0 - ts1);
    const double lt0 = (1.0 - al0) * ls0,       lt1 = (1.0 - al1) * ls1;
    const double rw0 = (1.0 - ga0) * rs0,       rw1 = (1.0 - ga1) * rs1;
    const double om_ga0 = 1.0 - ga0, om_ga1 = 1.0 - ga1;

    double v0 = 0.0, v1 = 0.0;
    bool y0 = false, y1 = false;

    const size_t bn = (size_t)b * N + n;
    const float* txp = tx + bn;
    float* op = out + bn;
    const float* cp = conduct + n;
    const size_t strideTx = (size_t)B * N;

    for (int t = 0; t < T; ++t) {
        const float2 x = *(const float2*)txp;
        const double ic0 = 1.0 - be0 * (1.0 - dsig((double)cp[0]));
        const double ic1 = 1.0 - be1 * (1.0 - dsig((double)cp[1]));

        const double I0 = (double)x.x * ic0;
        const double m0 = y0 ? om_ga0 : 1.0;
        const double r0 = y0 ? rw0 : 0.0;
        v0 = dv0 * v0 * m0 - lt0 + I0 - r0;
        y0 = v0 > th0;

        const double I1 = (double)x.y * ic1;
        const double m1 = y1 ? om_ga1 : 1.0;
        const double r1 = y1 ? rw1 : 0.0;
        v1 = dv1 * v1 * m1 - lt1 + I1 - r1;
        y1 = v1 > th1;

        float2 o;
        o.x = y0 ? 1.0f : 0.0f;
        o.y = y1 ? 1.0f : 0.0f;
        *(float2*)op = o;

        txp += strideTx;
        op += strideTx;
        cp += N;
    }
}

extern "C" void kernel_launch(void* const* d_in, const int* in_sizes, int n_in,
                              void* d_out, int out_size, void* d_ws, size_t ws_size,
                              hipStream_t stream) {
    const float* tx      = (const float*)d_in[0];
    const float* alpha   = (const float*)d_in[1];
    const float* beta    = (const float*)d_in[2];
    const float* gamma   = (const float*)d_in[3];
    const float* tau     = (const float*)d_in[4];
    const float* Vth     = (const float*)d_in[5];
    const float* leak    = (const float*)d_in[6];
    const float* reVth   = (const float*)d_in[7];
    const float* conduct = (const float*)d_in[8];
    float* out = (float*)d_out;

    const int N  = in_sizes[1];        // 2048
    const int TN = in_sizes[8];        // T*N = 131072
    const int T  = TN / N;             // 64
    const int B  = in_sizes[0] / TN;   // 128

    const size_t needed = (size_t)(5 * N + TN) * sizeof(double);
    if (ws_size >= needed) {
        double* wsd = (double*)d_ws;
        const int preBlocks = (TN + 255) / 256;
        glif_pre_kernel<<<preBlocks, 256, 0, stream>>>(
            alpha, beta, gamma, tau, Vth, leak, reVth, conduct, wsd, N, TN);
        const int total = B * N;
        glif_main_pf_kernel<<<(total + 255) / 256, 256, 0, stream>>>(
            tx, wsd, out, T, B, N);
    } else {
        const int total = B * (N >> 1);
        glif_main_inline_kernel<<<(total + 255) / 256, 256, 0, stream>>>(
            tx, alpha, beta, gamma, tau, Vth, leak, reVth, conduct,
            out, T, B, N);
    }
}

// Round 6
// 138.402 us; speedup vs baseline: 1.1375x; 1.0089x over previous
//
#include <hip/hip_runtime.h>
#include <math.h>

// GLIF forward scan. T=64, B=128, N=2048 (derived at runtime from in_sizes).
// All recurrence math in float64: output is 0/1 spikes with threshold 2e-2,
// one flip = fail. f64 error ~1e-16 vs closest spike margin ~1e-7 => safe.
//
// Round-6: 2 neurons/thread + D=8 double-buffered register prefetch.
// History: r3 4n/thread no-depth -> 48us (latency-bound, occ 8.7%);
// r4 1n/thread no-depth -> 50us (occupancy is NOT the limiter);
// r5 1n/thread D=8 -> ~26us (per-wave MLP is the limiter; fixed).
// r6 doubles per-inst width (8B x, 16B ic, 8B store = 512 B/wave) to halve
// VMEM instruction count while keeping 4 KB/wave outstanding.

typedef float  fx2 __attribute__((ext_vector_type(2)));
typedef double dx2 __attribute__((ext_vector_type(2)));

__device__ __forceinline__ double dsig(double x) {
    return 1.0 / (1.0 + exp(-x));
}

// Precompute kernel: one thread per (t,n) element of icoef; threads with
// i < N additionally compute the per-n constants.
// ws layout (doubles): [0,N) decay_v | [N,2N) leak_term | [2N,3N) reset_w
//                      | [3N,4N) thr | [4N,5N) ga | [5N, 5N+T*N) icoef
__global__ void glif_pre_kernel(const float* __restrict__ alpha,
                                const float* __restrict__ beta,
                                const float* __restrict__ gamma,
                                const float* __restrict__ tau,
                                const float* __restrict__ Vth,
                                const float* __restrict__ leak,
                                const float* __restrict__ reVth,
                                const float* __restrict__ conduct,
                                double* __restrict__ wsd,
                                int N, int TN) {
    int i = blockIdx.x * blockDim.x + threadIdx.x;
    if (i >= TN) return;
    int n = i % N;
    double be = dsig((double)beta[n]);
    double cs = dsig((double)conduct[i]);
    wsd[5 * N + i] = 1.0 - be * (1.0 - cs);  // icoef[t][n]
    if (i < N) {
        double al     = dsig((double)alpha[i]);
        double ga     = dsig((double)gamma[i]);
        double tau_s  = dsig((double)tau[i]);
        double vth_s  = dsig((double)Vth[i]);
        double leak_s = dsig((double)leak[i]);
        double rev_s  = dsig((double)reVth[i]);
        wsd[0 * N + i] = 1.0 - al * (1.0 - tau_s);  // decay_v
        wsd[1 * N + i] = (1.0 - al) * leak_s;       // leak_term
        wsd[2 * N + i] = (1.0 - ga) * rev_s;        // reset_w
        wsd[3 * N + i] = vth_s;                     // thr
        wsd[4 * N + i] = ga;                        // ga
    }
}

// Main scan: 2 neurons/thread, T blocked by D=8 with register double-buffer.
__global__ __launch_bounds__(256) void glif_main2_pf_kernel(
        const float* __restrict__ tx,
        const double* __restrict__ wsd,
        float* __restrict__ out,
        int T, int B, int N) {
    constexpr int D = 8;
    const int half = N >> 1;
    const int idx = blockIdx.x * blockDim.x + threadIdx.x;
    if (idx >= B * half) return;
    const int b = idx / half;
    const int n = (idx - b * half) << 1;

    const double dv0 = wsd[0 * N + n],  dv1 = wsd[0 * N + n + 1];
    const double lt0 = wsd[1 * N + n],  lt1 = wsd[1 * N + n + 1];
    const double rw0 = wsd[2 * N + n],  rw1 = wsd[2 * N + n + 1];
    const double th0 = wsd[3 * N + n],  th1 = wsd[3 * N + n + 1];
    const double omga0 = 1.0 - wsd[4 * N + n];      // (1-ga), exact: ga*1 == ga
    const double omga1 = 1.0 - wsd[4 * N + n + 1];

    const size_t bn = (size_t)b * N + n;
    const size_t stride = (size_t)B * N;   // elements between t-slices (x/out)
    const float*  txp = tx + bn;           // fx2 loads (8-byte aligned: n even)
    const double* icp = wsd + 5 * N + n;   // dx2 loads (16-byte aligned)
    float* op = out + bn;

    double v0 = 0.0, v1 = 0.0;
    bool y0 = false, y1 = false;

    const int nblk = T / D;

    fx2 xa[D], xb[D];
    dx2 ica[D], icb[D];

    // Load block 0 (16 independent loads in flight immediately).
#pragma unroll
    for (int j = 0; j < D; ++j) {
        xa[j]  = __builtin_nontemporal_load((const fx2*)(txp + (size_t)j * stride));
        ica[j] = *(const dx2*)(icp + (size_t)j * N);
    }

    for (int blk = 0; blk < nblk; ++blk) {
        const float*  txn = txp + (size_t)D * stride;
        const double* icn = icp + (size_t)D * N;
        const bool more = (blk + 1 < nblk);
        if (more) {
            // Issue next block's loads before touching this block's data:
            // they stay outstanding across the whole compute chain below.
#pragma unroll
            for (int j = 0; j < D; ++j) {
                xb[j]  = __builtin_nontemporal_load((const fx2*)(txn + (size_t)j * stride));
                icb[j] = *(const dx2*)(icn + (size_t)j * N);
            }
        }

#pragma unroll
        for (int j = 0; j < D; ++j) {
            // lane 0
            const double I0 = (double)xa[j].x * ica[j].x;
            const double m0 = y0 ? omga0 : 1.0;  // (1 - ga*y), exact for y in {0,1}
            const double r0 = y0 ? rw0 : 0.0;    // reset_w*y, exact
            v0 = dv0 * v0 * m0 - lt0 + I0 - r0;
            y0 = v0 > th0;
            // lane 1
            const double I1 = (double)xa[j].y * ica[j].y;
            const double m1 = y1 ? omga1 : 1.0;
            const double r1 = y1 ? rw1 : 0.0;
            v1 = dv1 * v1 * m1 - lt1 + I1 - r1;
            y1 = v1 > th1;

            fx2 o;
            o.x = y0 ? 1.0f : 0.0f;
            o.y = y1 ? 1.0f : 0.0f;
            __builtin_nontemporal_store(o, (fx2*)(op + (size_t)j * stride));
        }

        if (more) {
#pragma unroll
            for (int j = 0; j < D; ++j) { xa[j] = xb[j]; ica[j] = icb[j]; }
        }
        txp = txn; icp = icn; op += (size_t)D * stride;
    }

    // Remainder if T % D != 0 (dead for T=64).
    for (int t = nblk * D; t < T; ++t) {
        const fx2 x = *(const fx2*)txp;
        const dx2 ic = *(const dx2*)icp;
        const double I0 = (double)x.x * ic.x;
        const double m0 = y0 ? omga0 : 1.0;
        const double r0 = y0 ? rw0 : 0.0;
        v0 = dv0 * v0 * m0 - lt0 + I0 - r0;
        y0 = v0 > th0;
        const double I1 = (double)x.y * ic.y;
        const double m1 = y1 ? omga1 : 1.0;
        const double r1 = y1 ? rw1 : 0.0;
        v1 = dv1 * v1 * m1 - lt1 + I1 - r1;
        y1 = v1 > th1;
        fx2 o;
        o.x = y0 ? 1.0f : 0.0f;
        o.y = y1 ? 1.0f : 0.0f;
        *(fx2*)op = o;
        txp += stride; icp += N; op += stride;
    }
}

// Fallback (only if ws too small): computes all sigmoids inline per thread,
// 2 neurons/thread. Same f64 expression tree.
__global__ __launch_bounds__(256) void glif_main_inline_kernel(
        const float* __restrict__ tx,
        const float* __restrict__ alpha,
        const float* __restrict__ beta,
        const float* __restrict__ gamma,
        const float* __restrict__ tau,
        const float* __restrict__ Vth,
        const float* __restrict__ leak,
        const float* __restrict__ reVth,
        const float* __restrict__ conduct,
        float* __restrict__ out,
        int T, int B, int N) {
    const int half = N >> 1;
    const int idx = blockIdx.x * blockDim.x + threadIdx.x;
    if (idx >= B * half) return;
    const int b = idx / half;
    const int n = (idx - b * half) << 1;

    const double al0 = dsig((double)alpha[n]), al1 = dsig((double)alpha[n + 1]);
    const double ga0 = dsig((double)gamma[n]), ga1 = dsig((double)gamma[n + 1]);
    const double be0 = dsig((double)beta[n]),  be1 = dsig((double)beta[n + 1]);
    const double ts0 = dsig((double)tau[n]),   ts1 = dsig((double)tau[n + 1]);
    const double th0 = dsig((double)Vth[n]),   th1 = dsig((double)Vth[n + 1]);
    const double ls0 = dsig((double)leak[n]),  ls1 = dsig((double)leak[n + 1]);
    const double rs0 = dsig((double)reVth[n]), rs1 = dsig((double)reVth[n + 1]);
    const double dv0 = 1.0 - al0 * (1.0 - ts0), dv1 = 1.0 - al1 * (1.0 - ts1);
    const double lt0 = (1.0 - al0) * ls0,       lt1 = (1.0 - al1) * ls1;
    const double rw0 = (1.0 - ga0) * rs0,       rw1 = (1.0 - ga1) * rs1;
    const double om_ga0 = 1.0 - ga0, om_ga1 = 1.0 - ga1;

    double v0 = 0.0, v1 = 0.0;
    bool y0 = false, y1 = false;

    const size_t bn = (size_t)b * N + n;
    const float* txp = tx + bn;
    float* op = out + bn;
    const float* cp = conduct + n;
    const size_t strideTx = (size_t)B * N;

    for (int t = 0; t < T; ++t) {
        const float2 x = *(const float2*)txp;
        const double ic0 = 1.0 - be0 * (1.0 - dsig((double)cp[0]));
        const double ic1 = 1.0 - be1 * (1.0 - dsig((double)cp[1]));

        const double I0 = (double)x.x * ic0;
        const double m0 = y0 ? om_ga0 : 1.0;
        const double r0 = y0 ? rw0 : 0.0;
        v0 = dv0 * v0 * m0 - lt0 + I0 - r0;
        y0 = v0 > th0;

        const double I1 = (double)x.y * ic1;
        const double m1 = y1 ? om_ga1 : 1.0;
        const double r1 = y1 ? rw1 : 0.0;
        v1 = dv1 * v1 * m1 - lt1 + I1 - r1;
        y1 = v1 > th1;

        float2 o;
        o.x = y0 ? 1.0f : 0.0f;
        o.y = y1 ? 1.0f : 0.0f;
        *(float2*)op = o;

        txp += strideTx;
        op += strideTx;
        cp += N;
    }
}

extern "C" void kernel_launch(void* const* d_in, const int* in_sizes, int n_in,
                              void* d_out, int out_size, void* d_ws, size_t ws_size,
                              hipStream_t stream) {
    const float* tx      = (const float*)d_in[0];
    const float* alpha   = (const float*)d_in[1];
    const float* beta    = (const float*)d_in[2];
    const float* gamma   = (const float*)d_in[3];
    const float* tau     = (const float*)d_in[4];
    const float* Vth     = (const float*)d_in[5];
    const float* leak    = (const float*)d_in[6];
    const float* reVth   = (const float*)d_in[7];
    const float* conduct = (const float*)d_in[8];
    float* out = (float*)d_out;

    const int N  = in_sizes[1];        // 2048
    const int TN = in_sizes[8];        // T*N = 131072
    const int T  = TN / N;             // 64
    const int B  = in_sizes[0] / TN;   // 128

    const size_t needed = (size_t)(5 * N + TN) * sizeof(double);
    if (ws_size >= needed && (N & 1) == 0) {
        double* wsd = (double*)d_ws;
        const int preBlocks = (TN + 255) / 256;
        glif_pre_kernel<<<preBlocks, 256, 0, stream>>>(
            alpha, beta, gamma, tau, Vth, leak, reVth, conduct, wsd, N, TN);
        const int total = B * (N >> 1);
        glif_main2_pf_kernel<<<(total + 255) / 256, 256, 0, stream>>>(
            tx, wsd, out, T, B, N);
    } else {
        const int total = B * (N >> 1);
        glif_main_inline_kernel<<<(total + 255) / 256, 256, 0, stream>>>(
            tx, alpha, beta, gamma, tau, Vth, leak, reVth, conduct,
            out, T, B, N);
    }
}